// Round 13
// baseline (363.287 us; speedup 1.0000x reference)
//
#include <hip/hip_runtime.h>
#include <hip/hip_bf16.h>

// FFB encoder, MI355X. Round 19: lean unfused body at 4 waves/SIMD.
// r18 resolved the register accounting: VGPR_Count is ARCH-only; acc regs
// add on top (r8: 128+128=256 at lb2; r16: 84+32=116>102 at lb5 -> spill;
// r18: 84+48=132<170 at lb3 -> clean). The unfused r14 body is 84+32=116
// unified -> fits a 128 budget = 4 waves/SIMD. This round buys +33% TLP
// (12->16 waves/CU) on a latency-bound kernel (VALU 85us, MFMA 55us, 24%
// neither-pipe at 3 waves/SIMD):
//  1) unfused loop (one acc at a time, 32 acc regs),
//  2) high-W streamed inline from L2 (r18-proven; no persistent hfr),
//  3) EP table in global (r10/r16-proven; half-wave broadcast lines),
//     LDS = 32KB X-dbuf only,
//  4) launch_bounds(256,4), grid 4096.
// Kill signal: WRITE>85MB or FETCH>20MB = spill -> revert to r18 as final.
// Numerics identical (absmax 0.005859).

typedef __bf16 bf16_t;
typedef __attribute__((ext_vector_type(8))) __bf16 bf16x8;
typedef __attribute__((ext_vector_type(4))) float f32x4;
typedef __attribute__((ext_vector_type(16))) float f32x16;

#define C56R 8.9126768f               // 56 / (2*pi)
#define INV7 0.14285714285714285f

// ws layout (bytes) — frag-linear, unchanged from r4-r18
#define OFF_WMF   0        // mid W hi  [7][4mt][8kc][64lane][8bf16]
#define OFF_WMFLO 229376   // mid W lo
#define OFF_WHF   458752   // high W hi
#define OFF_EPM   688128   // [7][2hf][4mt][16r] float4 {ap0, ap1, C56R*bm, C56R*bh}

union ChunkU { bf16x8 v; unsigned int d[4]; };

__device__ __forceinline__ unsigned short bfbits(float x) {
  bf16_t b = (bf16_t)x;
  return __builtin_bit_cast(unsigned short, b);
}
__device__ __forceinline__ float bf2f(unsigned short u) {
  return __builtin_bit_cast(float, (unsigned int)u << 16);
}
__device__ __forceinline__ void pack2(float v0, float v1,
                                      unsigned int& ph, unsigned int& pl) {
  unsigned short h0 = bfbits(v0), h1 = bfbits(v1);
  ph = (unsigned int)h0 | ((unsigned int)h1 << 16);
  float l0 = v0 - bf2f(h0), l1 = v1 - bf2f(h1);
  pl = (unsigned int)bfbits(l0) | ((unsigned int)bfbits(l1) << 16);
}

__global__ void ffb_prep(const float* __restrict__ ffnA, const float* __restrict__ sigma,
                         const float* __restrict__ Wm, const float* __restrict__ bm,
                         const float* __restrict__ Wh, const float* __restrict__ bh,
                         unsigned char* __restrict__ ws) {
  int i = blockIdx.x * 256 + threadIdx.x;  // 448*256 = 114688 exactly
  bf16_t* wmf = (bf16_t*)(ws + OFF_WMF);
  bf16_t* wml = (bf16_t*)(ws + OFF_WMFLO);
  bf16_t* whf = (bf16_t*)(ws + OFF_WHF);
  {
    // fragment reorder: [it][mt][kc][lane][j]
    int j    = i & 7;
    int lane = (i >> 3) & 63;
    int kc   = (i >> 9) & 7;
    int mt   = (i >> 12) & 3;
    int it   = i >> 14;                       // 0..6
    int ho   = (mt << 5) + (lane & 31);
    int hin  = (kc << 4) + ((lane >> 5) << 3) + j;
    int src  = (it << 14) + (ho << 7) + hin;
    float w  = Wm[src];
    bf16_t h = (bf16_t)w;
    wmf[i] = h;
    wml[i] = (bf16_t)(w - (float)h);
    whf[i] = (bf16_t)Wh[src];
  }
  if (i < 896) {
    int r  = i & 15;
    int mt = (i >> 4) & 3;
    int hf = (i >> 6) & 1;
    int it = i >> 7;                          // 0..6
    int h  = (mt << 5) + (r & 3) + ((r >> 2) << 3) + (hf << 2);
    float sg = sigma[it];
    f32x4 e;
    e.x = ffnA[it * 256 + h] * sg;
    e.y = ffnA[it * 256 + 128 + h] * sg;
    e.z = C56R * bm[it * 128 + h];
    e.w = C56R * bh[it * 128 + h];
    ((f32x4*)(ws + OFF_EPM))[i] = e;
  }
}

__launch_bounds__(256, 4)
__global__ void ffb_main(const float* __restrict__ pos,
                         const float* __restrict__ gfeat,
                         const float* __restrict__ W0,
                         const float* __restrict__ b0,
                         const unsigned char* __restrict__ ws,
                         float* __restrict__ out) {
  // LDS: X double-buffer only: [dbuf:2][hi/lo][kc:8][lane:64][16B] = 32KB
  __shared__ __align__(16) unsigned char sX0[32768];

  const int tid  = threadIdx.x;
  const int L    = tid & 63;
  const int sub  = tid >> 6;        // wave 0..3 = mt tile owned
  const int p    = L & 31;
  const int hf   = L >> 5;
  const int n    = (blockIdx.x << 5) + p;

  const bf16_t* __restrict__ WMH = (const bf16_t*)(ws + OFF_WMF);
  const bf16_t* __restrict__ WML = (const bf16_t*)(ws + OFF_WMFLO);
  const bf16_t* __restrict__ WHF = (const bf16_t*)(ws + OFF_WHF);
  const f32x4*  __restrict__ EPM = (const f32x4*)(ws + OFF_EPM);
  const float*  __restrict__ EPW = (const float*)(ws + OFF_EPM);

  // ---- prefetch mid-W level 0 into registers (persistent mh/ml only)
  bf16x8 mh[8], ml[8];
  {
    const bf16_t* wh0 = WMH + (sub << 12) + (L << 3);
    const bf16_t* wl0 = WML + (sub << 12) + (L << 3);
    #pragma unroll
    for (int kc = 0; kc < 8; ++kc) {
      mh[kc] = *(const bf16x8*)(wh0 + (kc << 9));
      ml[kc] = *(const bf16x8*)(wl0 + (kc << 9));
    }
  }

  const float p0 = pos[n * 3 + 0], p1 = pos[n * 3 + 1], p2 = pos[n * 3 + 2];
  if (sub == 0 && hf == 0) {
    out[(size_t)n * 131 + 0] = (p0 + 1.f) * 0.5f;
    out[(size_t)n * 131 + 1] = (p1 + 1.f) * 0.5f;
    out[(size_t)n * 131 + 2] = (p2 + 1.f) * 0.5f;
  }

  // ---- layer 0: each wave fills its 2 X chunks (B-frag layout), buffer 0.
  #pragma unroll
  for (int cc = 0; cc < 2; ++cc) {
    const int c = (sub << 1) + cc;
    ChunkU chi, clo;
    #pragma unroll
    for (int jp = 0; jp < 4; ++jp) {
      int h0 = (c << 4) + (hf << 3) + 2 * jp;
      float d0 = __builtin_fmaf(p2, W0[h0*3+2], __builtin_fmaf(p1, W0[h0*3+1], p0 * W0[h0*3+0]));
      float d1 = __builtin_fmaf(p2, W0[h0*3+5], __builtin_fmaf(p1, W0[h0*3+4], p0 * W0[h0*3+3]));
      float v0 = __builtin_amdgcn_sinf(C56R * (d0 + b0[h0]));
      float v1 = __builtin_amdgcn_sinf(C56R * (d1 + b0[h0 + 1]));
      pack2(v0, v1, chi.d[jp], clo.d[jp]);
    }
    *(bf16x8*)(sX0 + (c << 10) + (L << 4))        = chi.v;
    *(bf16x8*)(sX0 + 8192 + (c << 10) + (L << 4)) = clo.v;
  }
  __syncthreads();   // X0 visible

  f32x16 buf;
  #pragma unroll
  for (int r = 0; r < 16; ++r) buf[r] = 0.f;

  #pragma unroll 1
  for (int it = 0; it < 8; ++it) {
    unsigned char* rb = sX0 + ((it & 1) << 14);        // X(it)
    unsigned char* wb = sX0 + (((it + 1) & 1) << 14);  // X(it+1) target

    // ---- high pass: level it-1, W streamed inline from L2 (r18 pattern)
    if (it > 0) {
      f32x16 acc;
      #pragma unroll
      for (int r = 0; r < 16; ++r) acc[r] = 0.f;
      const bf16_t* whb = WHF + ((it - 1) << 14) + (sub << 12) + (L << 3);
      #pragma unroll
      for (int kc = 0; kc < 8; ++kc) {
        bf16x8 hfrk = *(const bf16x8*)(whb + (kc << 9));
        bf16x8 xhc = *(const bf16x8*)(rb + (kc << 10) + (L << 4));
        acc = __builtin_amdgcn_mfma_f32_32x32x16_bf16(hfrk, xhc, acc, 0, 0, 0);
      }
      const int eb = ((((it - 1) << 1) + hf) * 4 + sub) * 16;
      #pragma unroll
      for (int r = 0; r < 16; ++r) {
        float cbh = EPW[(eb + r) * 4 + 3];
        buf[r] += __builtin_amdgcn_sinf(__builtin_fmaf(acc[r], C56R, cbh));
      }
    }

    // ---- mid pass: level it, W already in mh/ml[] ----
    if (it < 7) {
      f32x16 acc;
      #pragma unroll
      for (int r = 0; r < 16; ++r) acc[r] = 0.f;
      #pragma unroll
      for (int kc = 0; kc < 8; ++kc) {
        bf16x8 xhc = *(const bf16x8*)(rb + (kc << 10) + (L << 4));
        bf16x8 xlc = *(const bf16x8*)(rb + 8192 + (kc << 10) + (L << 4));
        acc = __builtin_amdgcn_mfma_f32_32x32x16_bf16(mh[kc], xhc, acc, 0, 0, 0);
        acc = __builtin_amdgcn_mfma_f32_32x32x16_bf16(ml[kc], xhc, acc, 0, 0, 0);
        acc = __builtin_amdgcn_mfma_f32_32x32x16_bf16(mh[kc], xlc, acc, 0, 0, 0);
      }

      // prefetch mid-W for level it+1 (consumed next body; crosses barrier)
      if (it < 6) {
        const bf16_t* wh = WMH + ((it + 1) << 14) + (sub << 12) + (L << 3);
        const bf16_t* wl = WML + ((it + 1) << 14) + (sub << 12) + (L << 3);
        #pragma unroll
        for (int kc = 0; kc < 8; ++kc) {
          mh[kc] = *(const bf16x8*)(wh + (kc << 9));
          ml[kc] = *(const bf16x8*)(wl + (kc << 9));
        }
      }

      // epilogue: x(it+1) = sin(grid) + sin(56*mid+b); b64 writes to OTHER
      // buffer -> no read-protection barrier needed before this.
      const float g0 = gfeat[n * 17 + 3 + 2 * it];
      const float g1 = gfeat[n * 17 + 4 + 2 * it];
      const int eb = (((it << 1) + hf) * 4 + sub) * 16;
      #pragma unroll
      for (int q = 0; q < 4; ++q) {
        const int r0 = q << 2;
        float v[4];
        #pragma unroll
        for (int k = 0; k < 4; ++k) {
          const int r = r0 + k;
          f32x4 e = EPM[eb + r];
          float sg = __builtin_amdgcn_sinf(__builtin_amdgcn_fractf(__builtin_fmaf(g1, e.y, g0 * e.x)));
          float sm = __builtin_amdgcn_sinf(__builtin_fmaf(acc[r], C56R, e.z));
          v[k] = sg + sm;
        }
        unsigned int ph0, pl0, ph1, pl1;
        pack2(v[0], v[1], ph0, pl0);
        pack2(v[2], v[3], ph1, pl1);
        unsigned long long qh = (unsigned long long)ph0 | ((unsigned long long)ph1 << 32);
        unsigned long long ql = (unsigned long long)pl0 | ((unsigned long long)pl1 << 32);
        const int c   = (sub << 1) + (r0 >> 3);
        const int bit = (r0 >> 2) & 1;
        const int off = (c << 10) + ((p + (bit << 5)) << 4) + (hf << 3);
        *(unsigned long long*)(wb + off)        = qh;
        *(unsigned long long*)(wb + 8192 + off) = ql;
      }
      __syncthreads();   // X(it+1) visible; only barrier this level
    }
  }

  // ---- final store: this wave's mt=sub rows for its 32 points.
  float* op = out + (size_t)n * 131 + 3;
  #pragma unroll
  for (int r = 0; r < 16; ++r) {
    const int h = (sub << 5) + (r & 3) + ((r >> 2) << 3) + (hf << 2);
    op[h] = buf[r] * INV7;
  }
}

extern "C" void kernel_launch(void* const* d_in, const int* in_sizes, int n_in,
                              void* d_out, int out_size, void* d_ws, size_t ws_size,
                              hipStream_t stream) {
  (void)in_sizes; (void)n_in; (void)out_size; (void)ws_size;
  const float* pos   = (const float*)d_in[0];
  const float* gfeat = (const float*)d_in[1];
  const float* ffnA  = (const float*)d_in[2];
  const float* sigma = (const float*)d_in[3];
  const float* W0    = (const float*)d_in[4];
  const float* b0    = (const float*)d_in[5];
  const float* Wm    = (const float*)d_in[6];
  const float* bm    = (const float*)d_in[7];
  const float* Wh    = (const float*)d_in[8];
  const float* bh    = (const float*)d_in[9];
  float* out = (float*)d_out;
  unsigned char* ws = (unsigned char*)d_ws;

  hipLaunchKernelGGL(ffb_prep, dim3(448), dim3(256), 0, stream,
                     ffnA, sigma, Wm, bm, Wh, bh, ws);
  hipLaunchKernelGGL(ffb_main, dim3(4096), dim3(256), 0, stream,
                     pos, gfeat, W0, b0, ws, out);
}

// Round 14
// 255.570 us; speedup vs baseline: 1.4215x; 1.4215x over previous
//
#include <hip/hip_runtime.h>
#include <hip/hip_bf16.h>

// FFB encoder, MI355X. Round 20 (FINAL): revert to r18 champion per r19's
// pre-committed kill signal (WRITE 144MB spill at lb(256,4); 4-waves axis
// dead -- allocator peak ~130-140 unified vs 128 budget). r18 = best
// measured: main dispatch 184us, zero spill (84 arch + 48 acc = 132 <= 170
// at lb(256,3)), FETCH 8MB / WRITE 71MB clean.
// Structure: fused high(it-1)+mid(it) kc-loop (one xh ds_read feeds both;
// 16 ds_read_b128/level), compiler-scheduled high-W stream from L2 (no
// persistent hfr -- stalled hfr load delays only accH, accM chain runs),
// persistent mh/ml mid-W prefetch arrays (whole-level ahead), X hi/lo
// double-buffer in LDS (epilogue writes other buffer -> 1 barrier/level),
// stride-17 EP table in LDS (bank-disjoint hf halves), b64 X writes.
// Session ledger: 231 (r7 start) -> 188.7 (r14 dbuf) -> 184 (r18 fusion);
// dead axes (all measured): occupancy >3 waves/EU (5 spills), >132-reg
// per-wave state (r15/r17), hand scheduling vs compiler (r12/r13).

typedef __bf16 bf16_t;
typedef __attribute__((ext_vector_type(8))) __bf16 bf16x8;
typedef __attribute__((ext_vector_type(4))) float f32x4;
typedef __attribute__((ext_vector_type(16))) float f32x16;

#define C56R 8.9126768f               // 56 / (2*pi)
#define INV7 0.14285714285714285f

// ws layout (bytes) — frag-linear, unchanged from r4-r19
#define OFF_WMF   0        // mid W hi  [7][4mt][8kc][64lane][8bf16]
#define OFF_WMFLO 229376   // mid W lo
#define OFF_WHF   458752   // high W hi
#define OFF_EPM   688128   // [7][2hf][4mt][16r] float4 {ap0, ap1, C56R*bm, C56R*bh}

union ChunkU { bf16x8 v; unsigned int d[4]; };

__device__ __forceinline__ unsigned short bfbits(float x) {
  bf16_t b = (bf16_t)x;
  return __builtin_bit_cast(unsigned short, b);
}
__device__ __forceinline__ float bf2f(unsigned short u) {
  return __builtin_bit_cast(float, (unsigned int)u << 16);
}
__device__ __forceinline__ void pack2(float v0, float v1,
                                      unsigned int& ph, unsigned int& pl) {
  unsigned short h0 = bfbits(v0), h1 = bfbits(v1);
  ph = (unsigned int)h0 | ((unsigned int)h1 << 16);
  float l0 = v0 - bf2f(h0), l1 = v1 - bf2f(h1);
  pl = (unsigned int)bfbits(l0) | ((unsigned int)bfbits(l1) << 16);
}

__global__ void ffb_prep(const float* __restrict__ ffnA, const float* __restrict__ sigma,
                         const float* __restrict__ Wm, const float* __restrict__ bm,
                         const float* __restrict__ Wh, const float* __restrict__ bh,
                         unsigned char* __restrict__ ws) {
  int i = blockIdx.x * 256 + threadIdx.x;  // 448*256 = 114688 exactly
  bf16_t* wmf = (bf16_t*)(ws + OFF_WMF);
  bf16_t* wml = (bf16_t*)(ws + OFF_WMFLO);
  bf16_t* whf = (bf16_t*)(ws + OFF_WHF);
  {
    // fragment reorder: [it][mt][kc][lane][j]
    int j    = i & 7;
    int lane = (i >> 3) & 63;
    int kc   = (i >> 9) & 7;
    int mt   = (i >> 12) & 3;
    int it   = i >> 14;                       // 0..6
    int ho   = (mt << 5) + (lane & 31);
    int hin  = (kc << 4) + ((lane >> 5) << 3) + j;
    int src  = (it << 14) + (ho << 7) + hin;
    float w  = Wm[src];
    bf16_t h = (bf16_t)w;
    wmf[i] = h;
    wml[i] = (bf16_t)(w - (float)h);
    whf[i] = (bf16_t)Wh[src];
  }
  if (i < 896) {
    int r  = i & 15;
    int mt = (i >> 4) & 3;
    int hf = (i >> 6) & 1;
    int it = i >> 7;                          // 0..6
    int h  = (mt << 5) + (r & 3) + ((r >> 2) << 3) + (hf << 2);
    float sg = sigma[it];
    f32x4 e;
    e.x = ffnA[it * 256 + h] * sg;
    e.y = ffnA[it * 256 + 128 + h] * sg;
    e.z = C56R * bm[it * 128 + h];
    e.w = C56R * bh[it * 128 + h];
    ((f32x4*)(ws + OFF_EPM))[i] = e;
  }
}

__launch_bounds__(256, 3)
__global__ void ffb_main(const float* __restrict__ pos,
                         const float* __restrict__ gfeat,
                         const float* __restrict__ W0,
                         const float* __restrict__ b0,
                         const unsigned char* __restrict__ ws,
                         float* __restrict__ out) {
  // LDS: [0,32K) X double-buffer (2 x {hi 8K, lo 8K});
  //      [32K, 32K+15232) epilogue consts, stride 17 f32x4
  __shared__ __align__(16) unsigned char smem[48000];
  unsigned char* sX0 = smem;
  f32x4* sEPv = (f32x4*)(smem + 32768);
  float* sEPf = (float*)(smem + 32768);

  const int tid  = threadIdx.x;
  const int L    = tid & 63;
  const int sub  = tid >> 6;        // wave 0..3 = mt tile owned
  const int p    = L & 31;
  const int hf   = L >> 5;
  const int n    = (blockIdx.x << 5) + p;

  const bf16_t* __restrict__ WMH = (const bf16_t*)(ws + OFF_WMF);
  const bf16_t* __restrict__ WML = (const bf16_t*)(ws + OFF_WMFLO);
  const bf16_t* __restrict__ WHF = (const bf16_t*)(ws + OFF_WHF);
  const f32x4*  __restrict__ EPM = (const f32x4*)(ws + OFF_EPM);

  // ---- prefetch mid-W level 0 into registers (r14-proven pattern)
  bf16x8 mh[8], ml[8];
  {
    const bf16_t* wh0 = WMH + (sub << 12) + (L << 3);
    const bf16_t* wl0 = WML + (sub << 12) + (L << 3);
    #pragma unroll
    for (int kc = 0; kc < 8; ++kc) {
      mh[kc] = *(const bf16x8*)(wh0 + (kc << 9));
      ml[kc] = *(const bf16x8*)(wl0 + (kc << 9));
    }
  }

  // ---- stage epilogue constants to LDS (stride 17: hf halves bank-disjoint)
  #pragma unroll
  for (int c = 0; c < 4; ++c) {
    int idx = tid + (c << 8);
    if (idx < 896) sEPv[(idx >> 4) * 17 + (idx & 15)] = EPM[idx];
  }

  const float p0 = pos[n * 3 + 0], p1 = pos[n * 3 + 1], p2 = pos[n * 3 + 2];
  if (sub == 0 && hf == 0) {
    out[(size_t)n * 131 + 0] = (p0 + 1.f) * 0.5f;
    out[(size_t)n * 131 + 1] = (p1 + 1.f) * 0.5f;
    out[(size_t)n * 131 + 2] = (p2 + 1.f) * 0.5f;
  }

  // ---- layer 0: each wave fills its 2 X chunks (B-frag layout), buffer 0.
  #pragma unroll
  for (int cc = 0; cc < 2; ++cc) {
    const int c = (sub << 1) + cc;
    ChunkU chi, clo;
    #pragma unroll
    for (int jp = 0; jp < 4; ++jp) {
      int h0 = (c << 4) + (hf << 3) + 2 * jp;
      float d0 = __builtin_fmaf(p2, W0[h0*3+2], __builtin_fmaf(p1, W0[h0*3+1], p0 * W0[h0*3+0]));
      float d1 = __builtin_fmaf(p2, W0[h0*3+5], __builtin_fmaf(p1, W0[h0*3+4], p0 * W0[h0*3+3]));
      float v0 = __builtin_amdgcn_sinf(C56R * (d0 + b0[h0]));
      float v1 = __builtin_amdgcn_sinf(C56R * (d1 + b0[h0 + 1]));
      pack2(v0, v1, chi.d[jp], clo.d[jp]);
    }
    *(bf16x8*)(sX0 + (c << 10) + (L << 4))        = chi.v;
    *(bf16x8*)(sX0 + 8192 + (c << 10) + (L << 4)) = clo.v;
  }
  __syncthreads();   // X0 + epilogue constants visible

  f32x16 buf;
  #pragma unroll
  for (int r = 0; r < 16; ++r) buf[r] = 0.f;

  // ================= it = 0: mid-only prologue =================
  {
    unsigned char* rb = sX0;           // X0
    unsigned char* wb = sX0 + 16384;   // X1 target

    f32x16 accM;
    #pragma unroll
    for (int r = 0; r < 16; ++r) accM[r] = 0.f;
    #pragma unroll
    for (int kc = 0; kc < 8; ++kc) {
      bf16x8 xhc = *(const bf16x8*)(rb + (kc << 10) + (L << 4));
      bf16x8 xlc = *(const bf16x8*)(rb + 8192 + (kc << 10) + (L << 4));
      accM = __builtin_amdgcn_mfma_f32_32x32x16_bf16(mh[kc], xhc, accM, 0, 0, 0);
      accM = __builtin_amdgcn_mfma_f32_32x32x16_bf16(ml[kc], xhc, accM, 0, 0, 0);
      accM = __builtin_amdgcn_mfma_f32_32x32x16_bf16(mh[kc], xlc, accM, 0, 0, 0);
    }

    // prefetch mid-W level 1
    {
      const bf16_t* wh = WMH + (1 << 14) + (sub << 12) + (L << 3);
      const bf16_t* wl = WML + (1 << 14) + (sub << 12) + (L << 3);
      #pragma unroll
      for (int kc = 0; kc < 8; ++kc) {
        mh[kc] = *(const bf16x8*)(wh + (kc << 9));
        ml[kc] = *(const bf16x8*)(wl + (kc << 9));
      }
    }

    // epilogue level 0 -> X1
    const float g0 = gfeat[n * 17 + 3];
    const float g1 = gfeat[n * 17 + 4];
    const int eb17 = ((hf) * 4 + sub) * 17;
    #pragma unroll
    for (int q = 0; q < 4; ++q) {
      const int r0 = q << 2;
      float v[4];
      #pragma unroll
      for (int k = 0; k < 4; ++k) {
        const int r = r0 + k;
        f32x4 e = sEPv[eb17 + r];
        float sg = __builtin_amdgcn_sinf(__builtin_amdgcn_fractf(__builtin_fmaf(g1, e.y, g0 * e.x)));
        float sm = __builtin_amdgcn_sinf(__builtin_fmaf(accM[r], C56R, e.z));
        v[k] = sg + sm;
      }
      unsigned int ph0, pl0, ph1, pl1;
      pack2(v[0], v[1], ph0, pl0);
      pack2(v[2], v[3], ph1, pl1);
      unsigned long long qh = (unsigned long long)ph0 | ((unsigned long long)ph1 << 32);
      unsigned long long ql = (unsigned long long)pl0 | ((unsigned long long)pl1 << 32);
      const int c   = (sub << 1) + (r0 >> 3);
      const int bit = (r0 >> 2) & 1;
      const int off = (c << 10) + ((p + (bit << 5)) << 4) + (hf << 3);
      *(unsigned long long*)(wb + off)        = qh;
      *(unsigned long long*)(wb + 8192 + off) = ql;
    }
    __syncthreads();   // X1 visible
  }

  // ====== it = 1..6: fused high(it-1) + mid(it), streamed high-W ======
  #pragma unroll 1
  for (int it = 1; it < 7; ++it) {
    unsigned char* rb = sX0 + ((it & 1) << 14);        // X(it)
    unsigned char* wb = sX0 + (((it + 1) & 1) << 14);  // X(it+1) target

    f32x16 accH, accM;
    #pragma unroll
    for (int r = 0; r < 16; ++r) { accH[r] = 0.f; accM[r] = 0.f; }

    // fused kc loop: one xh read feeds high(it-1) AND mid(it); high-W
    // loaded from L2 inside the loop (compiler schedules the prefetch).
    const bf16_t* whb = WHF + ((it - 1) << 14) + (sub << 12) + (L << 3);
    #pragma unroll
    for (int kc = 0; kc < 8; ++kc) {
      bf16x8 hfrk = *(const bf16x8*)(whb + (kc << 9));
      bf16x8 xhc = *(const bf16x8*)(rb + (kc << 10) + (L << 4));
      bf16x8 xlc = *(const bf16x8*)(rb + 8192 + (kc << 10) + (L << 4));
      accH = __builtin_amdgcn_mfma_f32_32x32x16_bf16(hfrk,   xhc, accH, 0, 0, 0);
      accM = __builtin_amdgcn_mfma_f32_32x32x16_bf16(mh[kc], xhc, accM, 0, 0, 0);
      accM = __builtin_amdgcn_mfma_f32_32x32x16_bf16(ml[kc], xhc, accM, 0, 0, 0);
      accM = __builtin_amdgcn_mfma_f32_32x32x16_bf16(mh[kc], xlc, accM, 0, 0, 0);
    }

    // prefetch mid-W level it+1 (mh/ml consumed above; r14-proven pattern)
    if (it < 6) {
      const bf16_t* wh = WMH + ((it + 1) << 14) + (sub << 12) + (L << 3);
      const bf16_t* wl = WML + ((it + 1) << 14) + (sub << 12) + (L << 3);
      #pragma unroll
      for (int kc = 0; kc < 8; ++kc) {
        mh[kc] = *(const bf16x8*)(wh + (kc << 9));
        ml[kc] = *(const bf16x8*)(wl + (kc << 9));
      }
    }

    // buf finish for level it-1 (accH chain completed early in fused loop)
    {
      const int ebp17 = ((((it - 1) << 1) + hf) * 4 + sub) * 17;
      #pragma unroll
      for (int r = 0; r < 16; ++r) {
        float cbh = sEPf[(ebp17 + r) * 4 + 3];
        buf[r] += __builtin_amdgcn_sinf(__builtin_fmaf(accH[r], C56R, cbh));
      }
    }

    // epilogue level it -> X(it+1); b64 writes
    const float g0 = gfeat[n * 17 + 3 + 2 * it];
    const float g1 = gfeat[n * 17 + 4 + 2 * it];
    const int eb17 = (((it << 1) + hf) * 4 + sub) * 17;
    #pragma unroll
    for (int q = 0; q < 4; ++q) {
      const int r0 = q << 2;
      float v[4];
      #pragma unroll
      for (int k = 0; k < 4; ++k) {
        const int r = r0 + k;
        f32x4 e = sEPv[eb17 + r];
        float sg = __builtin_amdgcn_sinf(__builtin_amdgcn_fractf(__builtin_fmaf(g1, e.y, g0 * e.x)));
        float sm = __builtin_amdgcn_sinf(__builtin_fmaf(accM[r], C56R, e.z));
        v[k] = sg + sm;
      }
      unsigned int ph0, pl0, ph1, pl1;
      pack2(v[0], v[1], ph0, pl0);
      pack2(v[2], v[3], ph1, pl1);
      unsigned long long qh = (unsigned long long)ph0 | ((unsigned long long)ph1 << 32);
      unsigned long long ql = (unsigned long long)pl0 | ((unsigned long long)pl1 << 32);
      const int c   = (sub << 1) + (r0 >> 3);
      const int bit = (r0 >> 2) & 1;
      const int off = (c << 10) + ((p + (bit << 5)) << 4) + (hf << 3);
      *(unsigned long long*)(wb + off)        = qh;
      *(unsigned long long*)(wb + 8192 + off) = ql;
    }
    __syncthreads();   // X(it+1) visible; only barrier this level
  }

  // ================= it = 7: high-only peel (level 6) =================
  {
    unsigned char* rb = sX0 + 16384;   // X7 = buffer 1
    f32x16 accH;
    #pragma unroll
    for (int r = 0; r < 16; ++r) accH[r] = 0.f;
    const bf16_t* whb = WHF + (6 << 14) + (sub << 12) + (L << 3);
    #pragma unroll
    for (int kc = 0; kc < 8; ++kc) {
      bf16x8 hfrk = *(const bf16x8*)(whb + (kc << 9));
      bf16x8 xhc = *(const bf16x8*)(rb + (kc << 10) + (L << 4));
      accH = __builtin_amdgcn_mfma_f32_32x32x16_bf16(hfrk, xhc, accH, 0, 0, 0);
    }
    const int ebp17 = (((6 << 1) + hf) * 4 + sub) * 17;
    #pragma unroll
    for (int r = 0; r < 16; ++r) {
      float cbh = sEPf[(ebp17 + r) * 4 + 3];
      buf[r] += __builtin_amdgcn_sinf(__builtin_fmaf(accH[r], C56R, cbh));
    }
  }

  // ---- final store: this wave's mt=sub rows for its 32 points.
  float* op = out + (size_t)n * 131 + 3;
  #pragma unroll
  for (int r = 0; r < 16; ++r) {
    const int h = (sub << 5) + (r & 3) + ((r >> 2) << 3) + (hf << 2);
    op[h] = buf[r] * INV7;
  }
}

extern "C" void kernel_launch(void* const* d_in, const int* in_sizes, int n_in,
                              void* d_out, int out_size, void* d_ws, size_t ws_size,
                              hipStream_t stream) {
  (void)in_sizes; (void)n_in; (void)out_size; (void)ws_size;
  const float* pos   = (const float*)d_in[0];
  const float* gfeat = (const float*)d_in[1];
  const float* ffnA  = (const float*)d_in[2];
  const float* sigma = (const float*)d_in[3];
  const float* W0    = (const float*)d_in[4];
  const float* b0    = (const float*)d_in[5];
  const float* Wm    = (const float*)d_in[6];
  const float* bm    = (const float*)d_in[7];
  const float* Wh    = (const float*)d_in[8];
  const float* bh    = (const float*)d_in[9];
  float* out = (float*)d_out;
  unsigned char* ws = (unsigned char*)d_ws;

  hipLaunchKernelGGL(ffb_prep, dim3(448), dim3(256), 0, stream,
                     ffnA, sigma, Wm, bm, Wh, bh, ws);
  hipLaunchKernelGGL(ffb_main, dim3(4096), dim3(256), 0, stream,
                     pos, gfeat, W0, b0, ws, out);
}